// Round 8
// baseline (331.268 us; speedup 1.0000x reference)
//
#include <hip/hip_runtime.h>
#include <cstdint>
#include <cstddef>

// N=100000, E=300000, B=50000, L=4, D_EMB=128, D_HID=64, H=8. fp32 in/out.
// R10: (1) k_dense __launch_bounds__(256,4): R9's VGPR=64 (8-wave target)
// left ZERO spare regs -> B-loads serialized at L2 latency. 128-VGPR budget
// lets compiler pipeline the 64 B-frag loads. (2) scan1+scan23 merged into
// one co-resident publish/poll kernel (write-once flag words, 64B stride).
// (3) gatefinal folded into k_output (per-block redundant gate reduce).
// Dispatches: 7 (memset, prep, dense(+hist), scan, scatter_logits,
//                node_agg, output(+gate)).

typedef __attribute__((ext_vector_type(8))) short bf16x8;
typedef __attribute__((ext_vector_type(4))) float f32x4;
typedef __attribute__((ext_vector_type(8))) unsigned short u16x8;

__device__ __forceinline__ unsigned short f2bf(float f) {
    unsigned u = __float_as_uint(f);
    unsigned r = u + 0x7fffu + ((u >> 16) & 1u);
    return (unsigned short)(r >> 16);
}
__device__ __forceinline__ float bf2f(unsigned short h) {
    return __uint_as_float((unsigned)h << 16);
}
// monotonic float<->unsigned order-preserving encode (for atomicMax)
__device__ __forceinline__ unsigned fenc(float f) {
    unsigned u = __float_as_uint(f);
    return (u & 0x80000000u) ? ~u : (u | 0x80000000u);
}
__device__ __forceinline__ float fdec(unsigned k) {
    unsigned u = (k & 0x80000000u) ? (k & 0x7fffffffu) : ~k;
    return __uint_as_float(u);
}

// ---------------------------------------------------------------------------
// Pack B = [Wi;Wp].T (K=128 x N=128) into MFMA B-frag order, split hi/lo bf16.
// Fused: batch-node multiplicity histogram.
__global__ __launch_bounds__(256) void k_prep(
    const float* __restrict__ Wi, const float* __restrict__ Wp,
    unsigned short* __restrict__ Whi, unsigned short* __restrict__ Wlo,
    const int* __restrict__ batch_nodes, int* __restrict__ mult, int B) {
    int t = blockIdx.x * 256 + threadIdx.x;
    if (t < B) atomicAdd(&mult[batch_nodes[t]], 1);
    if (t >= 16384) return;
    int j = t & 7, L = (t >> 3) & 63, c = (t >> 9) & 7, s = t >> 12;
    int k = s * 32 + (L >> 4) * 8 + j;
    int n = c * 16 + (L & 15);
    float v = (n < 64) ? Wi[n * 128 + k] : Wp[(n - 64) * 128 + k];
    unsigned short h = f2bf(v);
    Whi[t] = h;
    Wlo[t] = f2bf(v - bf2f(h));
}

// ---------------------------------------------------------------------------
// Dense GEMM: Ybf[M x 128] = feat[M x 128] @ B, split-bf16 (3 MFMA per tile).
// No LDS, no barriers. 128-VGPR budget (min 4 waves/EU) so the compiler can
// keep many B-frag loads in flight across the unrolled s/c loops.
__global__ __launch_bounds__(256, 4) void k_dense(
    const float* __restrict__ feat, const unsigned short* __restrict__ Whi,
    const unsigned short* __restrict__ Wlo, const float* __restrict__ attn,
    const int* __restrict__ edge_dst, const int* __restrict__ mult,
    int* __restrict__ count, unsigned short* __restrict__ Ybf,
    float* __restrict__ P, int M, int E) {
    int t = threadIdx.x;

    // edge-hist prologue (grid covers E: 1563 * 256 = 400k > 300k)
    {
        int e = blockIdx.x * 256 + t;
        if (e < E) {
            int d = edge_dst[e];
            if (mult[d] > 0) atomicAdd(&count[d], 1);
        }
    }

    int L = t & 63;
    int wave = t >> 6;
    int m = L & 15, q = L >> 4;
    int R0 = blockIdx.x * 64 + wave * 16;

    int rowc = R0 + m; if (rowc > M - 1) rowc = M - 1;
    const float* arow = feat + (size_t)rowc * 128;

    // hoist ALL A loads (8 x float4 = full 512B row slice for this lane)
    float4 av0[4], av1[4];
#pragma unroll
    for (int s = 0; s < 4; ++s) {
        const float4* ap = (const float4*)(arow + s * 32 + q * 8);
        av0[s] = ap[0];
        av1[s] = ap[1];
    }
    // convert all A to split hi/lo bf16 upfront
    bf16x8 ahi[4], alo[4];
#pragma unroll
    for (int s = 0; s < 4; ++s) {
        float av[8] = {av0[s].x, av0[s].y, av0[s].z, av0[s].w,
                       av1[s].x, av1[s].y, av1[s].z, av1[s].w};
#pragma unroll
        for (int j = 0; j < 8; ++j) {
            unsigned short h = f2bf(av[j]);
            ahi[s][j] = (short)h;
            alo[s][j] = (short)f2bf(av[j] - bf2f(h));
        }
    }

    f32x4 acc[8];
#pragma unroll
    for (int c = 0; c < 8; ++c) acc[c] = (f32x4){0.f, 0.f, 0.f, 0.f};

    const bf16x8* gh = (const bf16x8*)Whi;
    const bf16x8* gl = (const bf16x8*)Wlo;
#pragma unroll
    for (int s = 0; s < 4; ++s) {
#pragma unroll
        for (int c = 0; c < 8; ++c) {
            bf16x8 bh = gh[(s * 8 + c) * 64 + L];
            bf16x8 bl = gl[(s * 8 + c) * 64 + L];
            acc[c] = __builtin_amdgcn_mfma_f32_16x16x32_bf16(ahi[s], bh, acc[c], 0, 0, 0);
            acc[c] = __builtin_amdgcn_mfma_f32_16x16x32_bf16(ahi[s], bl, acc[c], 0, 0, 0);
            acc[c] = __builtin_amdgcn_mfma_f32_16x16x32_bf16(alo[s], bh, acc[c], 0, 0, 0);
        }
    }

    // C/D layout: col = lane&15 (=m), row = (lane>>4)*4 + reg (=q*4+r)
#pragma unroll
    for (int c = 0; c < 8; ++c) {
#pragma unroll
        for (int r = 0; r < 4; ++r) {
            int row = R0 + q * 4 + r;
            if (row < M) Ybf[(size_t)row * 128 + c * 16 + m] = f2bf(acc[c][r]);
        }
    }
    // P epilogue: P[row,i] = Yi[row].attn_i, P[row,8+i] = Yp[row].attn_i.
#pragma unroll
    for (int i = 0; i < 8; ++i) {
        float a0 = attn[i * 64 + m];
        float a1 = attn[i * 64 + 16 + m];
        float a2 = attn[i * 64 + 32 + m];
        float a3 = attn[i * 64 + 48 + m];
#pragma unroll
        for (int r = 0; r < 4; ++r) {
            int row = R0 + q * 4 + r;
            float pi = acc[0][r] * a0 + acc[1][r] * a1 + acc[2][r] * a2 + acc[3][r] * a3;
            float pp = acc[4][r] * a0 + acc[5][r] * a1 + acc[6][r] * a2 + acc[7][r] * a3;
#pragma unroll
            for (int o = 1; o < 16; o <<= 1) {
                pi += __shfl_xor(pi, o);
                pp += __shfl_xor(pp, o);
            }
            if (row < M) {
                if (m == i)     P[(size_t)row * 16 + i] = pi;
                if (m == i + 8) P[(size_t)row * 16 + 8 + i] = pp;
            }
        }
    }
}

// ---------------------------------------------------------------------------
// Single-kernel scan: per-block local scan, publish aggregate (flag|value,
// release), poll predecessors (all blocks co-resident: 391 blocks << chip),
// write offsets/cursor. state[bid*16] is a write-once word, 64B stride.
#define SCAN_FLAG 0x40000000u
__global__ __launch_bounds__(256) void k_scan(
    const int* __restrict__ count, int* __restrict__ offsets,
    int* __restrict__ cursor, unsigned* __restrict__ state, int N) {
    __shared__ int lds[256];
    int bid = blockIdx.x, t = threadIdx.x;
    int i = bid * 256 + t;
    int c = (i < N) ? count[i] : 0;
    lds[t] = c; __syncthreads();
    for (int o = 1; o < 256; o <<= 1) {
        int v = (t >= o) ? lds[t - o] : 0;
        __syncthreads(); lds[t] += v; __syncthreads();
    }
    int incl = lds[t];
    int total = lds[255];
    int excl = incl - c;
    if (t == 0)
        __hip_atomic_store(&state[(size_t)bid * 16], (unsigned)total | SCAN_FLAG,
                           __ATOMIC_RELEASE, __HIP_MEMORY_SCOPE_AGENT);
    // poll predecessors (distributed over threads)
    int s = 0;
    for (int j = t; j < bid; j += 256) {
        unsigned v;
        do {
            v = __hip_atomic_load(&state[(size_t)j * 16], __ATOMIC_ACQUIRE,
                                  __HIP_MEMORY_SCOPE_AGENT);
        } while (!(v & SCAN_FLAG));
        s += (int)(v & (SCAN_FLAG - 1u));
    }
    __syncthreads();           // lds reads (incl/total) done; safe to reuse
    lds[t] = s; __syncthreads();
#pragma unroll
    for (int o = 128; o > 0; o >>= 1) {
        if (t < o) lds[t] += lds[t + o];
        __syncthreads();
    }
    int boff = lds[0];
    if (i < N) {
        int off = boff + excl;
        offsets[i] = off; cursor[i] = off;
    }
    if (t == 255 && bid == gridDim.x - 1) offsets[N] = boff + total;
}

// ---------------------------------------------------------------------------
// Fused scatter + logits + per-(node,head) max (float-ordered atomicMax).
// 8 lanes per edge (h = lane&7).
__global__ __launch_bounds__(256) void k_scatter_logits(
    const int* __restrict__ edge_dst, const int* __restrict__ mult,
    int* __restrict__ cursor, const int* __restrict__ mp,
    const float* __restrict__ P, const float* __restrict__ Wth,
    float* __restrict__ logits, int4* __restrict__ mpc,
    unsigned* __restrict__ mxkey, int E) {
    int e = blockIdx.x * 32 + (threadIdx.x >> 3);
    if (e >= E) return;
    int h = threadIdx.x & 7;
    int d = edge_dst[e];
    if (mult[d] == 0) return;
    int pos = 0;
    if (h == 0) pos = atomicAdd(&cursor[d], 1);
    int gbase = threadIdx.x & ~7;
    pos = __shfl(pos, gbase);
    int4 rows = *(const int4*)(mp + (size_t)e * 4);
    float s = P[(size_t)rows.x * 16 + h] + P[(size_t)rows.w * 16 + h]
            + P[(size_t)rows.y * 16 + 8 + h] + P[(size_t)rows.z * 16 + 8 + h];
    float l = 0.f;
#pragma unroll
    for (int j = 0; j < 8; ++j) {
        float sj = __shfl(s, gbase + j);
        l += Wth[h * 8 + j] * sj;
    }
    l = l > 0.f ? l : 0.01f * l;
    logits[(size_t)pos * 8 + h] = l;
    atomicMax(&mxkey[(size_t)d * 8 + h], fenc(l));
    if (h == 0) mpc[pos] = rows;
}

// ---------------------------------------------------------------------------
// Per flagged node: single-pass plain softmax (max precomputed in mxkey) +
// aggregation from Ybf. One wave per node, lane = d. 8 exps/edge.
__global__ __launch_bounds__(256) void k_node_agg(
    const unsigned short* __restrict__ Ybf, const float* __restrict__ logits,
    const int4* __restrict__ mpc, const int* __restrict__ offsets,
    const int* __restrict__ mult, const unsigned* __restrict__ mxkey,
    const float* __restrict__ Wg,
    unsigned short* __restrict__ nftb, float* __restrict__ gate_part, int N) {
    int n = blockIdx.x * 4 + (threadIdx.x >> 6);
    int lane = threadIdx.x & 63;
    if (n >= N) return;
    int m = mult[n];
    if (m == 0) return;
    int beg = offsets[n], end = offsets[n + 1];

    float mx[8], den[8], acc[8];
#pragma unroll
    for (int h = 0; h < 8; ++h) {
        mx[h] = fdec(mxkey[(size_t)n * 8 + h]);
        den[h] = 0.f; acc[h] = 0.f;
    }

    for (int j = beg; j < end; ++j) {
        const float4* lp = (const float4*)(logits + (size_t)j * 8);
        float4 l0 = lp[0], l1 = lp[1];
        int4 rows = mpc[j];
        float ed = bf2f(Ybf[(size_t)rows.x * 128 + lane])
                 + bf2f(Ybf[(size_t)rows.w * 128 + lane])
                 + bf2f(Ybf[(size_t)rows.y * 128 + 64 + lane])
                 + bf2f(Ybf[(size_t)rows.z * 128 + 64 + lane]);
        float w0 = __expf(l0.x - mx[0]), w1 = __expf(l0.y - mx[1]);
        float w2 = __expf(l0.z - mx[2]), w3 = __expf(l0.w - mx[3]);
        float w4 = __expf(l1.x - mx[4]), w5 = __expf(l1.y - mx[5]);
        float w6 = __expf(l1.z - mx[6]), w7 = __expf(l1.w - mx[7]);
        den[0] += w0; den[1] += w1; den[2] += w2; den[3] += w3;
        den[4] += w4; den[5] += w5; den[6] += w6; den[7] += w7;
        acc[0] += w0 * ed; acc[1] += w1 * ed; acc[2] += w2 * ed; acc[3] += w3 * ed;
        acc[4] += w4 * ed; acc[5] += w5 * ed; acc[6] += w6 * ed; acc[7] += w7 * ed;
    }

#pragma unroll
    for (int h = 0; h < 8; ++h) {
        float r = (end > beg) ? 1.f / den[h] : 0.f;
        acc[h] *= r;
    }

    unsigned short* base = nftb + (size_t)n * 512;
#pragma unroll
    for (int h = 0; h < 8; ++h) base[h * 64 + lane] = f2bf(acc[h]);

    float wg = Wg[lane];
    float myg = 0.f;
#pragma unroll
    for (int h = 0; h < 8; ++h) {
        float p = acc[h] * wg;
#pragma unroll
        for (int o = 32; o > 0; o >>= 1) p += __shfl_xor(p, o);
        if (lane == h) myg = p;
    }
    if (lane < 8)
        atomicAdd(&gate_part[(blockIdx.x & 1023) * 8 + lane], (float)m * myg);
}

// ---------------------------------------------------------------------------
// Output with folded gate reduction: each block redundantly reduces
// gate_part (L2-resident), then grid-strides the gated gather-store.
__global__ __launch_bounds__(256) void k_output(
    const unsigned short* __restrict__ nftb, const int* __restrict__ batch_nodes,
    const float* __restrict__ gate_part, const float* __restrict__ b_gate,
    float* __restrict__ out, int B) {
    __shared__ float lds[256];
    __shared__ float sg[8];
    int t = threadIdx.x;
    {
        int h = t & 7, g = t >> 3;
        float s = 0.f;
        for (int b = g; b < 1024; b += 32) s += gate_part[b * 8 + h];
        lds[t] = s; __syncthreads();
        if (t < 8) {
            float tot = 0.f;
            for (int gg = 0; gg < 32; ++gg) tot += lds[gg * 8 + t];
            sg[t] = tot / (float)B + b_gate[0];
        }
        __syncthreads();
    }
    int total = B * 64;
    int stride = gridDim.x * 256;
    for (int idx = blockIdx.x * 256 + t; idx < total; idx += stride) {
        int b = idx >> 6;
        int r = idx & 63;
        int h = r >> 3;
        int n = batch_nodes[b];
        u16x8 v = *(const u16x8*)(nftb + (size_t)n * 512 + r * 8);
        float g = sg[h];
        f32x4 o0, o1;
        o0[0] = bf2f(v[0]) * g; o0[1] = bf2f(v[1]) * g;
        o0[2] = bf2f(v[2]) * g; o0[3] = bf2f(v[3]) * g;
        o1[0] = bf2f(v[4]) * g; o1[1] = bf2f(v[5]) * g;
        o1[2] = bf2f(v[6]) * g; o1[3] = bf2f(v[7]) * g;
        f32x4* op = (f32x4*)(out + (size_t)idx * 8);
        __builtin_nontemporal_store(o0, op);
        __builtin_nontemporal_store(o1, op + 1);
    }
}

// ---------------------------------------------------------------------------
extern "C" void kernel_launch(void* const* d_in, const int* in_sizes, int n_in,
                              void* d_out, int out_size, void* d_ws, size_t ws_size,
                              hipStream_t stream) {
    const int*   batch_nodes = (const int*)d_in[0];
    const int*   mp          = (const int*)d_in[1];
    const int*   edge_dst    = (const int*)d_in[2];
    const float* feat        = (const float*)d_in[3];
    const float* W_i         = (const float*)d_in[4];
    const float* W_p         = (const float*)d_in[5];
    const float* attn        = (const float*)d_in[6];
    const float* W_th        = (const float*)d_in[7];
    const float* W_gate      = (const float*)d_in[8];
    const float* b_gate      = (const float*)d_in[9];
    float* out = (float*)d_out;

    const int B = in_sizes[0];
    const int E = in_sizes[2];
    const int N = in_sizes[3] / 128;
    const int nb_scan = (N + 255) / 256;

    char* w = (char*)d_ws;
    auto alloc = [&](size_t bytes) -> void* {
        void* p = (void*)w;
        w += (bytes + 255) & ~(size_t)255;
        return p;
    };
    unsigned short* Whi = (unsigned short*)alloc(16384 * 2);
    unsigned short* Wlo = (unsigned short*)alloc(16384 * 2);
    unsigned short* Ybf = (unsigned short*)alloc((size_t)N * 128 * 2);   // 25.6 MB
    float* P            = (float*)alloc((size_t)N * 16 * 4);             // 6.4 MB
    float* logits       = (float*)alloc((size_t)E * 8 * 4);              // 9.6 MB
    int4*  mpc          = (int4*)alloc((size_t)E * 16);                  // 4.8 MB
    // contiguous zero region: mult | count | gate_part | mxkey | scan_state
    size_t zero_ints    = (size_t)N + (size_t)N + 8192 + (size_t)N * 8 + 512 * 16;
    int*   mult         = (int*)alloc(zero_ints * 4);
    int*   count        = mult + N;
    float* gate_part    = (float*)(count + N);
    unsigned* mxkey     = (unsigned*)(gate_part + 8192);
    unsigned* sstate    = mxkey + (size_t)N * 8;
    int*   offsets      = (int*)alloc((size_t)(N + 1) * 4);
    int*   cursor       = (int*)alloc((size_t)N * 4);
    unsigned short* nftb = (unsigned short*)alloc((size_t)N * 512 * 2);  // 102.4 MB
    float* gate         = (float*)alloc(256);
    (void)gate;

    hipMemsetAsync(mult, 0, zero_ints * 4, stream);

    int prep_work = (B > 16384) ? B : 16384;
    k_prep<<<(prep_work + 255) / 256, 256, 0, stream>>>(W_i, W_p, Whi, Wlo,
                                                        batch_nodes, mult, B);
    k_dense<<<(N + 63) / 64, 256, 0, stream>>>(feat, Whi, Wlo, attn,
                                               edge_dst, mult, count, Ybf, P, N, E);
    k_scan<<<nb_scan, 256, 0, stream>>>(count, offsets, cursor, sstate, N);
    k_scatter_logits<<<(E + 31) / 32, 256, 0, stream>>>(edge_dst, mult, cursor,
                                                        mp, P, W_th, logits, mpc,
                                                        mxkey, E);
    k_node_agg<<<(N + 3) / 4, 256, 0, stream>>>(Ybf, logits, mpc, offsets, mult,
                                                mxkey, W_gate, nftb, gate_part, N);
    k_output<<<2048, 256, 0, stream>>>(nftb, batch_nodes, gate_part, b_gate, out, B);
}

// Round 9
// 307.792 us; speedup vs baseline: 1.0763x; 1.0763x over previous
//
#include <hip/hip_runtime.h>
#include <cstdint>
#include <cstddef>

// N=100000, E=300000, B=50000, L=4, D_EMB=128, D_HID=64, H=8. fp32 in/out.
// R11: kill k_dense's shuffle epilogue. P[n,i] = feat[n]@(W^T@attn_i), so P
// is 16 extra GEMM columns vs precomputed Wcomb (built in k_prep, split-bf16
// B-frags). k_dense stores P straight from the MFMA accumulator -> zero
// cross-lane DS ops (R7-R10: ~512 ds_swizzle/wave, hidden DS-pipe cost).
// Scan (scan1+scan23), gatefinal, output reverted to proven R7/R9 shapes
// (R10 merge cost ~16us). atomicMax-hoisted softmax max kept (R7).
// Dispatches: 9 (memset, prep, dense(+hist), scan1, scan23, scatter_logits,
//                node_agg, gatefinal, output).

typedef __attribute__((ext_vector_type(8))) short bf16x8;
typedef __attribute__((ext_vector_type(4))) float f32x4;
typedef __attribute__((ext_vector_type(8))) unsigned short u16x8;

__device__ __forceinline__ unsigned short f2bf(float f) {
    unsigned u = __float_as_uint(f);
    unsigned r = u + 0x7fffu + ((u >> 16) & 1u);
    return (unsigned short)(r >> 16);
}
__device__ __forceinline__ float bf2f(unsigned short h) {
    return __uint_as_float((unsigned)h << 16);
}
// monotonic float<->unsigned order-preserving encode (for atomicMax)
__device__ __forceinline__ unsigned fenc(float f) {
    unsigned u = __float_as_uint(f);
    return (u & 0x80000000u) ? ~u : (u | 0x80000000u);
}
__device__ __forceinline__ float fdec(unsigned k) {
    unsigned u = (k & 0x80000000u) ? (k & 0x7fffffffu) : ~k;
    return __uint_as_float(u);
}

// ---------------------------------------------------------------------------
// Pack B = [Wi;Wp].T (K=128 x N=128) into MFMA B-frag order, split hi/lo bf16.
// Also pack Wcomb[128x16] (col i<8: Wi^T@attn_i; col 8+i: Wp^T@attn_i) as a
// single extra B-frag tile (Phi/Plo). Fused: batch-node multiplicity hist.
__global__ __launch_bounds__(256) void k_prep(
    const float* __restrict__ Wi, const float* __restrict__ Wp,
    const float* __restrict__ attn,
    unsigned short* __restrict__ Whi, unsigned short* __restrict__ Wlo,
    unsigned short* __restrict__ Phi, unsigned short* __restrict__ Plo,
    const int* __restrict__ batch_nodes, int* __restrict__ mult, int B) {
    int t = blockIdx.x * 256 + threadIdx.x;
    if (t < B) atomicAdd(&mult[batch_nodes[t]], 1);
    if (t < 16384) {
        int j = t & 7, L = (t >> 3) & 63, c = (t >> 9) & 7, s = t >> 12;
        int k = s * 32 + (L >> 4) * 8 + j;
        int n = c * 16 + (L & 15);
        float v = (n < 64) ? Wi[n * 128 + k] : Wp[(n - 64) * 128 + k];
        unsigned short h = f2bf(v);
        Whi[t] = h;
        Wlo[t] = f2bf(v - bf2f(h));
    } else if (t < 16384 + 2048) {
        int t2 = t - 16384;
        int j = t2 & 7, L = (t2 >> 3) & 63, s = t2 >> 9;
        int k = s * 32 + (L >> 4) * 8 + j;
        int i = L & 15;
        const float* Wsrc = (i < 8) ? Wi : Wp;
        const float* av = attn + (size_t)(i & 7) * 64;
        float v = 0.f;
#pragma unroll 8
        for (int d = 0; d < 64; ++d) v += av[d] * Wsrc[d * 128 + k];
        unsigned short h = f2bf(v);
        Phi[t2] = h;
        Plo[t2] = f2bf(v - bf2f(h));
    }
}

// ---------------------------------------------------------------------------
// Dense GEMM: Ybf[M x 128] = feat[M x 128] @ B, split-bf16 (3 MFMA per tile),
// plus P[M x 16] = feat @ Wcomb as a 9th col-tile. No LDS, no barriers, no
// cross-lane ops. P stored directly from accumulator (C/D layout).
__global__ __launch_bounds__(256, 4) void k_dense(
    const float* __restrict__ feat, const unsigned short* __restrict__ Whi,
    const unsigned short* __restrict__ Wlo, const unsigned short* __restrict__ Phi,
    const unsigned short* __restrict__ Plo,
    const int* __restrict__ edge_dst, const int* __restrict__ mult,
    int* __restrict__ count, unsigned short* __restrict__ Ybf,
    float* __restrict__ P, int M, int E) {
    int t = threadIdx.x;

    // edge-hist prologue (grid covers E: 1563 * 256 = 400k > 300k)
    {
        int e = blockIdx.x * 256 + t;
        if (e < E) {
            int d = edge_dst[e];
            if (mult[d] > 0) atomicAdd(&count[d], 1);
        }
    }

    int L = t & 63;
    int wave = t >> 6;
    int m = L & 15, q = L >> 4;
    int R0 = blockIdx.x * 64 + wave * 16;

    int rowc = R0 + m; if (rowc > M - 1) rowc = M - 1;
    const float* arow = feat + (size_t)rowc * 128;

    // hoist ALL A loads (8 x float4 = full 512B row slice for this lane)
    float4 av0[4], av1[4];
#pragma unroll
    for (int s = 0; s < 4; ++s) {
        const float4* ap = (const float4*)(arow + s * 32 + q * 8);
        av0[s] = ap[0];
        av1[s] = ap[1];
    }
    // convert all A to split hi/lo bf16 upfront
    bf16x8 ahi[4], alo[4];
#pragma unroll
    for (int s = 0; s < 4; ++s) {
        float av[8] = {av0[s].x, av0[s].y, av0[s].z, av0[s].w,
                       av1[s].x, av1[s].y, av1[s].z, av1[s].w};
#pragma unroll
        for (int j = 0; j < 8; ++j) {
            unsigned short h = f2bf(av[j]);
            ahi[s][j] = (short)h;
            alo[s][j] = (short)f2bf(av[j] - bf2f(h));
        }
    }

    f32x4 acc[8];
#pragma unroll
    for (int c = 0; c < 8; ++c) acc[c] = (f32x4){0.f, 0.f, 0.f, 0.f};
    f32x4 accP = (f32x4){0.f, 0.f, 0.f, 0.f};

    const bf16x8* gh = (const bf16x8*)Whi;
    const bf16x8* gl = (const bf16x8*)Wlo;
    const bf16x8* ph = (const bf16x8*)Phi;
    const bf16x8* pl = (const bf16x8*)Plo;
#pragma unroll
    for (int s = 0; s < 4; ++s) {
#pragma unroll
        for (int c = 0; c < 8; ++c) {
            bf16x8 bh = gh[(s * 8 + c) * 64 + L];
            bf16x8 bl = gl[(s * 8 + c) * 64 + L];
            acc[c] = __builtin_amdgcn_mfma_f32_16x16x32_bf16(ahi[s], bh, acc[c], 0, 0, 0);
            acc[c] = __builtin_amdgcn_mfma_f32_16x16x32_bf16(ahi[s], bl, acc[c], 0, 0, 0);
            acc[c] = __builtin_amdgcn_mfma_f32_16x16x32_bf16(alo[s], bh, acc[c], 0, 0, 0);
        }
        {
            bf16x8 bh = ph[s * 64 + L];
            bf16x8 bl = pl[s * 64 + L];
            accP = __builtin_amdgcn_mfma_f32_16x16x32_bf16(ahi[s], bh, accP, 0, 0, 0);
            accP = __builtin_amdgcn_mfma_f32_16x16x32_bf16(ahi[s], bl, accP, 0, 0, 0);
            accP = __builtin_amdgcn_mfma_f32_16x16x32_bf16(alo[s], bh, accP, 0, 0, 0);
        }
    }

    // C/D layout: col = lane&15 (=m), row = (lane>>4)*4 + reg (=q*4+r)
#pragma unroll
    for (int c = 0; c < 8; ++c) {
#pragma unroll
        for (int r = 0; r < 4; ++r) {
            int row = R0 + q * 4 + r;
            if (row < M) Ybf[(size_t)row * 128 + c * 16 + m] = f2bf(acc[c][r]);
        }
    }
    // P store: col i = m, rows q*4+r
#pragma unroll
    for (int r = 0; r < 4; ++r) {
        int row = R0 + q * 4 + r;
        if (row < M) P[(size_t)row * 16 + m] = accP[r];
    }
}

// ---------------------------------------------------------------------------
// per-block exclusive scan of count + block partial sums
__global__ __launch_bounds__(256) void k_scan1(
    const int* __restrict__ count, int* __restrict__ excl, int* __restrict__ partials, int N) {
    __shared__ int lds[256];
    int t = threadIdx.x, i = blockIdx.x * 256 + t;
    int c = (i < N) ? count[i] : 0;
    lds[t] = c; __syncthreads();
    for (int o = 1; o < 256; o <<= 1) {
        int v = (t >= o) ? lds[t - o] : 0;
        __syncthreads(); lds[t] += v; __syncthreads();
    }
    if (i < N) excl[i] = lds[t] - c;
    if (t == 255) partials[blockIdx.x] = lds[255];
}

// merged scan2+scan3
__global__ __launch_bounds__(256) void k_scan23(
    const int* __restrict__ excl, const int* __restrict__ partials,
    int* __restrict__ offsets, int* __restrict__ cursor, int N) {
    __shared__ int sacc[256];
    int bid = blockIdx.x, t = threadIdx.x;
    int s = 0;
    for (int j = t; j < bid; j += 256) s += partials[j];
    sacc[t] = s; __syncthreads();
#pragma unroll
    for (int o = 128; o > 0; o >>= 1) {
        if (t < o) sacc[t] += sacc[t + o];
        __syncthreads();
    }
    int boff = sacc[0];
    int i = bid * 256 + t;
    if (i < N) {
        int o = excl[i] + boff;
        offsets[i] = o; cursor[i] = o;
    }
    if (t == 0 && bid == gridDim.x - 1) offsets[N] = boff + partials[bid];
}

// ---------------------------------------------------------------------------
// Fused scatter + logits + per-(node,head) max (float-ordered atomicMax).
// 8 lanes per edge (h = lane&7).
__global__ __launch_bounds__(256) void k_scatter_logits(
    const int* __restrict__ edge_dst, const int* __restrict__ mult,
    int* __restrict__ cursor, const int* __restrict__ mp,
    const float* __restrict__ P, const float* __restrict__ Wth,
    float* __restrict__ logits, int4* __restrict__ mpc,
    unsigned* __restrict__ mxkey, int E) {
    int e = blockIdx.x * 32 + (threadIdx.x >> 3);
    if (e >= E) return;
    int h = threadIdx.x & 7;
    int d = edge_dst[e];
    if (mult[d] == 0) return;
    int pos = 0;
    if (h == 0) pos = atomicAdd(&cursor[d], 1);
    int gbase = threadIdx.x & ~7;
    pos = __shfl(pos, gbase);
    int4 rows = *(const int4*)(mp + (size_t)e * 4);
    float s = P[(size_t)rows.x * 16 + h] + P[(size_t)rows.w * 16 + h]
            + P[(size_t)rows.y * 16 + 8 + h] + P[(size_t)rows.z * 16 + 8 + h];
    float l = 0.f;
#pragma unroll
    for (int j = 0; j < 8; ++j) {
        float sj = __shfl(s, gbase + j);
        l += Wth[h * 8 + j] * sj;
    }
    l = l > 0.f ? l : 0.01f * l;
    logits[(size_t)pos * 8 + h] = l;
    atomicMax(&mxkey[(size_t)d * 8 + h], fenc(l));
    if (h == 0) mpc[pos] = rows;
}

// ---------------------------------------------------------------------------
// Per flagged node: single-pass plain softmax (max precomputed in mxkey) +
// aggregation from Ybf. One wave per node, lane = d. 8 exps/edge.
__global__ __launch_bounds__(256) void k_node_agg(
    const unsigned short* __restrict__ Ybf, const float* __restrict__ logits,
    const int4* __restrict__ mpc, const int* __restrict__ offsets,
    const int* __restrict__ mult, const unsigned* __restrict__ mxkey,
    const float* __restrict__ Wg,
    unsigned short* __restrict__ nftb, float* __restrict__ gate_part, int N) {
    int n = blockIdx.x * 4 + (threadIdx.x >> 6);
    int lane = threadIdx.x & 63;
    if (n >= N) return;
    int m = mult[n];
    if (m == 0) return;
    int beg = offsets[n], end = offsets[n + 1];

    float mx[8], den[8], acc[8];
#pragma unroll
    for (int h = 0; h < 8; ++h) {
        mx[h] = fdec(mxkey[(size_t)n * 8 + h]);
        den[h] = 0.f; acc[h] = 0.f;
    }

    for (int j = beg; j < end; ++j) {
        const float4* lp = (const float4*)(logits + (size_t)j * 8);
        float4 l0 = lp[0], l1 = lp[1];
        int4 rows = mpc[j];
        float ed = bf2f(Ybf[(size_t)rows.x * 128 + lane])
                 + bf2f(Ybf[(size_t)rows.w * 128 + lane])
                 + bf2f(Ybf[(size_t)rows.y * 128 + 64 + lane])
                 + bf2f(Ybf[(size_t)rows.z * 128 + 64 + lane]);
        float w0 = __expf(l0.x - mx[0]), w1 = __expf(l0.y - mx[1]);
        float w2 = __expf(l0.z - mx[2]), w3 = __expf(l0.w - mx[3]);
        float w4 = __expf(l1.x - mx[4]), w5 = __expf(l1.y - mx[5]);
        float w6 = __expf(l1.z - mx[6]), w7 = __expf(l1.w - mx[7]);
        den[0] += w0; den[1] += w1; den[2] += w2; den[3] += w3;
        den[4] += w4; den[5] += w5; den[6] += w6; den[7] += w7;
        acc[0] += w0 * ed; acc[1] += w1 * ed; acc[2] += w2 * ed; acc[3] += w3 * ed;
        acc[4] += w4 * ed; acc[5] += w5 * ed; acc[6] += w6 * ed; acc[7] += w7 * ed;
    }

#pragma unroll
    for (int h = 0; h < 8; ++h) {
        float r = (end > beg) ? 1.f / den[h] : 0.f;
        acc[h] *= r;
    }

    unsigned short* base = nftb + (size_t)n * 512;
#pragma unroll
    for (int h = 0; h < 8; ++h) base[h * 64 + lane] = f2bf(acc[h]);

    float wg = Wg[lane];
    float myg = 0.f;
#pragma unroll
    for (int h = 0; h < 8; ++h) {
        float p = acc[h] * wg;
#pragma unroll
        for (int o = 32; o > 0; o >>= 1) p += __shfl_xor(p, o);
        if (lane == h) myg = p;
    }
    if (lane < 8)
        atomicAdd(&gate_part[(blockIdx.x & 1023) * 8 + lane], (float)m * myg);
}

// gate[h] = sum(gate_part)/B + b_gate
__global__ __launch_bounds__(256) void k_gatefinal(
    const float* __restrict__ gate_part, const float* __restrict__ b_gate,
    float* __restrict__ gate, int B) {
    __shared__ float lds[256];
    int t = threadIdx.x;
    int h = t & 7, g = t >> 3;
    float s = 0.f;
    for (int b = g; b < 1024; b += 32) s += gate_part[b * 8 + h];
    lds[t] = s; __syncthreads();
    if (t < 8) {
        float tot = 0.f;
        for (int gg = 0; gg < 32; ++gg) tot += lds[gg * 8 + t];
        gate[t] = tot / (float)B + b_gate[0];
    }
}

// out[b, h*64+d] = nftb[batch_nodes[b]] * gate[h]  -- 16B/lane, NT stores
__global__ __launch_bounds__(256) void k_output(
    const unsigned short* __restrict__ nftb, const int* __restrict__ batch_nodes,
    const float* __restrict__ gate, float* __restrict__ out, int B) {
    int idx = blockIdx.x * 256 + threadIdx.x;
    int total = B * 64;
    if (idx >= total) return;
    int b = idx >> 6;
    int r = idx & 63;
    int h = r >> 3;
    int n = batch_nodes[b];
    u16x8 v = *(const u16x8*)(nftb + (size_t)n * 512 + r * 8);
    float g = gate[h];
    f32x4 o0, o1;
    o0[0] = bf2f(v[0]) * g; o0[1] = bf2f(v[1]) * g;
    o0[2] = bf2f(v[2]) * g; o0[3] = bf2f(v[3]) * g;
    o1[0] = bf2f(v[4]) * g; o1[1] = bf2f(v[5]) * g;
    o1[2] = bf2f(v[6]) * g; o1[3] = bf2f(v[7]) * g;
    f32x4* op = (f32x4*)(out + (size_t)idx * 8);
    __builtin_nontemporal_store(o0, op);
    __builtin_nontemporal_store(o1, op + 1);
}

// ---------------------------------------------------------------------------
extern "C" void kernel_launch(void* const* d_in, const int* in_sizes, int n_in,
                              void* d_out, int out_size, void* d_ws, size_t ws_size,
                              hipStream_t stream) {
    const int*   batch_nodes = (const int*)d_in[0];
    const int*   mp          = (const int*)d_in[1];
    const int*   edge_dst    = (const int*)d_in[2];
    const float* feat        = (const float*)d_in[3];
    const float* W_i         = (const float*)d_in[4];
    const float* W_p         = (const float*)d_in[5];
    const float* attn        = (const float*)d_in[6];
    const float* W_th        = (const float*)d_in[7];
    const float* W_gate      = (const float*)d_in[8];
    const float* b_gate      = (const float*)d_in[9];
    float* out = (float*)d_out;

    const int B = in_sizes[0];
    const int E = in_sizes[2];
    const int N = in_sizes[3] / 128;
    const int nb_scan = (N + 255) / 256;

    char* w = (char*)d_ws;
    auto alloc = [&](size_t bytes) -> void* {
        void* p = (void*)w;
        w += (bytes + 255) & ~(size_t)255;
        return p;
    };
    unsigned short* Whi = (unsigned short*)alloc(16384 * 2);
    unsigned short* Wlo = (unsigned short*)alloc(16384 * 2);
    unsigned short* Phi = (unsigned short*)alloc(2048 * 2);
    unsigned short* Plo = (unsigned short*)alloc(2048 * 2);
    unsigned short* Ybf = (unsigned short*)alloc((size_t)N * 128 * 2);   // 25.6 MB
    float* P            = (float*)alloc((size_t)N * 16 * 4);             // 6.4 MB
    float* logits       = (float*)alloc((size_t)E * 8 * 4);              // 9.6 MB
    int4*  mpc          = (int4*)alloc((size_t)E * 16);                  // 4.8 MB
    // contiguous zero region: mult | count | gate_part | mxkey (single memset)
    size_t zero_bytes   = (size_t)N * 4 + (size_t)N * 4 + 1024 * 8 * 4
                        + (size_t)N * 8 * 4;
    int*   mult         = (int*)alloc(zero_bytes);
    int*   count        = mult + N;
    float* gate_part    = (float*)(count + N);
    unsigned* mxkey     = (unsigned*)(gate_part + 8192);
    int*   excl         = (int*)alloc((size_t)N * 4);
    int*   offsets      = (int*)alloc((size_t)(N + 1) * 4);
    int*   cursor       = (int*)alloc((size_t)N * 4);
    int*   partials     = (int*)alloc(512 * 4);
    unsigned short* nftb = (unsigned short*)alloc((size_t)N * 512 * 2);  // 102.4 MB
    float* gate         = (float*)alloc(256);

    hipMemsetAsync(mult, 0, zero_bytes, stream);

    int prep_work = (B > 16384 + 2048) ? B : 16384 + 2048;
    k_prep<<<(prep_work + 255) / 256, 256, 0, stream>>>(W_i, W_p, attn,
                                                        Whi, Wlo, Phi, Plo,
                                                        batch_nodes, mult, B);
    k_dense<<<(N + 63) / 64, 256, 0, stream>>>(feat, Whi, Wlo, Phi, Plo,
                                               edge_dst, mult, count, Ybf, P, N, E);
    k_scan1<<<nb_scan, 256, 0, stream>>>(count, excl, partials, N);
    k_scan23<<<nb_scan, 256, 0, stream>>>(excl, partials, offsets, cursor, N);
    k_scatter_logits<<<(E + 31) / 32, 256, 0, stream>>>(edge_dst, mult, cursor,
                                                        mp, P, W_th, logits, mpc,
                                                        mxkey, E);
    k_node_agg<<<(N + 3) / 4, 256, 0, stream>>>(Ybf, logits, mpc, offsets, mult,
                                                mxkey, W_gate, nftb, gate_part, N);
    k_gatefinal<<<1, 256, 0, stream>>>(gate_part, b_gate, gate, B);
    k_output<<<(B * 64 + 255) / 256, 256, 0, stream>>>(nftb, batch_nodes, gate, out, B);
}